// Round 13
// baseline (306.249 us; speedup 1.0000x reference)
//
#include <hip/hip_runtime.h>
#include <math.h>

constexpr int Cc = 3, Hh = 256;
constexpr int NX = 393216;                 // 2*3*256*256
constexpr int R = 8;                       // rows per block
constexpr int NBLK = 192;                  // 6 images * 32 tiles (1 block/CU)
constexpr int KSTEPS = 50;
constexpr int ROWQ = 128;                  // u64 per halo row (256 floats)
constexpr int BROWS = 12;                  // halo rows per block per slot
constexpr int SLOTQ = NBLK * BROWS * ROWQ; // u64 per slot
constexpr int WPS = NBLK * 8;              // parts words per step (one per wave) = 1536

using u64 = unsigned long long;
constexpr u64 SENT = 0x8000000080000000ull;  // (-0.0f,-0.0f): unreachable payload

__device__ __forceinline__ float4 ld4(const float* p, int i) { return ((const float4*)p)[i]; }
__device__ __forceinline__ void st4(float* p, int i, float4 v) { ((float4*)p)[i] = v; }
__device__ __forceinline__ float4 mk4(float a, float b, float c, float d) { return make_float4(a, b, c, d); }
__device__ __forceinline__ u64 ldq(const u64* p) {
    return __hip_atomic_load(p, __ATOMIC_RELAXED, __HIP_MEMORY_SCOPE_AGENT);
}
__device__ __forceinline__ void stq(u64* p, u64 v) {
    __hip_atomic_store(p, v, __ATOMIC_RELAXED, __HIP_MEMORY_SCOPE_AGENT);
}
__device__ __forceinline__ void pub4(u64* w, float4 v) {
    union { float f[2]; u64 q; } a, b;
    a.f[0] = v.x; a.f[1] = v.y; b.f[0] = v.z; b.f[1] = v.w;
    stq(w, a.q); stq(w + 1, b.q);
}
__device__ __forceinline__ float4 unp(u64 lo, u64 hi) {
    union { u64 q; float f[2]; } a, b; a.q = lo; b.q = hi;
    return make_float4(a.f[0], a.f[1], b.f[0], b.f[1]);
}
__device__ __forceinline__ float4 col3(float4 P, float4 A, float4 B, float a, float b) {
    return mk4(fmaf(a, A.x, fmaf(b, B.x, P.x)), fmaf(a, A.y, fmaf(b, B.y, P.y)),
               fmaf(a, A.z, fmaf(b, B.z, P.z)), fmaf(a, A.w, fmaf(b, B.w, P.w)));
}
__device__ __forceinline__ float4 f4sub(float4 a, float4 b) {
    return mk4(a.x - b.x, a.y - b.y, a.z - b.z, a.w - b.w);
}
__device__ __forceinline__ float4 f4s(float4 a, float s) {
    return mk4(a.x * s, a.y * s, a.z * s, a.w * s);
}
__device__ __forceinline__ float4 f4fma(float s, float4 a, float4 b) {   // s*a + b
    return mk4(fmaf(s, a.x, b.x), fmaf(s, a.y, b.y), fmaf(s, a.z, b.z), fmaf(s, a.w, b.w));
}
__device__ __forceinline__ float4 nth(float4 vm, bool up, float4 v0x, bool dn) {
    return mk4((up ? vm.x : 0.f) - (dn ? v0x.x : 0.f), (up ? vm.y : 0.f) - (dn ? v0x.y : 0.f),
               (up ? vm.z : 0.f) - (dn ? v0x.z : 0.f), (up ? vm.w : 0.f) - (dn ? v0x.w : 0.f));
}
__device__ __forceinline__ float4 ntw(float4 v1x, int c4) {
    float ul = __shfl_up(v1x.w, 1, 64);
    return mk4(((c4 > 0) ? ul : 0.f) - v1x.x, v1x.x - v1x.y, v1x.y - v1x.z,
               v1x.z - ((c4 < 63) ? v1x.w : 0.f));
}
__device__ __forceinline__ float4 gradw(float4 t, int c4) {
    float xn = __shfl_down(t.x, 1, 64);
    return mk4(t.y - t.x, t.z - t.y, t.w - t.z, (c4 < 63) ? (xn - t.w) : 0.f);
}
__device__ __forceinline__ void barld() {
    asm volatile("s_waitcnt lgkmcnt(0)" ::: "memory");
    __builtin_amdgcn_sched_barrier(0);
    __builtin_amdgcn_s_barrier();
    __builtin_amdgcn_sched_barrier(0);
}

__global__ void init_ws(u64* h0, u64* h1, u64* h2, u64* parts) {
    int i = blockIdx.x * 256 + threadIdx.x;
    if (i < SLOTQ) { h0[i] = SENT; h1[i] = SENT; h2[i] = SENT; }
    if (i < (KSTEPS + 1) * WPS) parts[i] = SENT;
}

__global__ void __launch_bounds__(512, 1) cp_persist(
    const float* __restrict__ y, const float* __restrict__ lambd,
    float* __restrict__ xout, float* __restrict__ xtout, float* __restrict__ uout,
    u64* __restrict__ h0, u64* __restrict__ h1, u64* __restrict__ h2,
    u64* __restrict__ parts)
{
    __shared__ float PCS[8][9][256];   // piece handoff: [row][field][col] (72 KB)
    __shared__ float sG[2];            // wave-3-polled global norm sums

    const int tid = threadIdx.x, blk = blockIdx.x;
    const int bc = blk >> 5, tile = blk & 31, r0 = tile * R;
    const int c4 = tid & 63, trow = tid >> 6;      // trow in [0,8)
    const int b = (bc >= Cc) ? 1 : 0;
    const float lamb = expf(lambd[0]);
    const int gh = r0 + trow;
    const int j4 = bc * 16384 + gh * 64 + c4;
    const bool have2 = (gh < Hh - 1);              // shadow row exists
    const bool dn2 = (gh < Hh - 2);                // shadow row's down-neighbor exists

    float4 pc[9];                                  // own piece fields
    float4 xcur, x2, v0c, v0c2, v1c, v1c2, vm;
    float4 yv, yv2;
    float tau = 0.20412414523193150818f, sig = tau, chi, sigs;

    auto slotp = [&](int r) -> u64* { return (r == 0) ? h0 : ((r == 1) ? h1 : h2); };
    auto ldsF = [&](int row, int f) -> float4& { return ((float4*)PCS[row][f])[c4]; };
    auto wavesum2 = [&](float& a, float& bb) {
        #pragma unroll
        for (int m = 1; m < 64; m <<= 1) { a += __shfl_xor(a, m, 64); bb += __shfl_xor(bb, m, 64); }
    };
    auto pollparts = [&](int s, float& g0, float& g1) {
        const u64* pb = parts + (size_t)s * WPS + b * 768 + c4 * 12;
        u64 t[12];
        for (;;) {
            #pragma unroll
            for (int i = 0; i < 12; ++i) t[i] = ldq(pb + i);
            bool ok = true;
            #pragma unroll
            for (int i = 0; i < 12; ++i) ok = ok && (t[i] != SENT);
            if (__all(ok)) break;
            __builtin_amdgcn_s_sleep(1);
        }
        asm volatile("" ::: "memory");
        g0 = 0.f; g1 = 0.f;
        #pragma unroll
        for (int i = 0; i < 12; ++i) { union { u64 q; float f[2]; } a; a.q = t[i]; g0 += a.f[0]; g1 += a.f[1]; }
        wavesum2(g0, g1);
    };
    auto normpub = [&](int sidx) {
        float pa0 = v0c.x*v0c.x + v0c.y*v0c.y + v0c.z*v0c.z + v0c.w*v0c.w;
        float pa1 = v1c.x*v1c.x + v1c.y*v1c.y + v1c.z*v1c.z + v1c.w*v1c.w;
        wavesum2(pa0, pa1);
        if (c4 == 0) {
            union { float f[2]; u64 q; } pk; pk.f[0] = pa0; pk.f[1] = pa1;
            stq(parts + (size_t)sidx * WPS + blk * 8 + trow, pk.q);
        }
    };
    // fused expansion: own xt pieces + shadow xt pieces (row r+1) -> dh locally; no LDS round-trip
    auto expandF = [&](int slot, bool pub) {
        const float inv = 1.f / (1.f + tau), tin = tau * inv, opc = 1.f + chi;
        float4 NT0 = nth(vm, gh > 0, v0c, have2);
        float4 NT1 = ntw(v1c, c4);
        float4 BASE = f4s(f4fma(tau, yv, xcur), inv);
        float4 xA = f4s(NT0, -tin), xB = f4s(NT1, -tin);
        float4 xtP = f4fma(-chi, xcur, f4s(BASE, opc)), xtA = f4s(xA, opc), xtB = f4s(xB, opc);
        float4 dhP = mk4(0, 0, 0, 0), dhA = dhP, dhB = dhP;
        if (have2) {
            // shadow row gh+1: vm = own v0c; identical helpers -> bit-exact vs owner
            float4 NT0b = nth(v0c, true, v0c2, dn2);
            float4 NT1b = ntw(v1c2, c4);
            float4 BASEb = f4s(f4fma(tau, yv2, x2), inv);
            float4 xAb = f4s(NT0b, -tin), xBb = f4s(NT1b, -tin);
            dhP = f4sub(f4fma(-chi, x2, f4s(BASEb, opc)), xtP);
            dhA = f4sub(f4s(xAb, opc), xtA);
            dhB = f4sub(f4s(xBb, opc), xtB);
        }
        float4 dwP = gradw(xtP, c4), dwA = gradw(xtA, c4), dwB = gradw(xtB, c4);
        pc[0] = BASE; pc[1] = xA; pc[2] = xB;
        pc[3] = f4s(dhP, sigs); pc[4] = f4fma(sigs, dhA, v0c); pc[5] = f4s(dhB, sigs);
        pc[6] = f4s(dwP, sigs); pc[7] = f4s(dwA, sigs); pc[8] = f4fma(sigs, dwB, v1c);
        #pragma unroll
        for (int f = 0; f < 9; ++f) ldsF(trow, f) = pc[f];
        if (pub) {
            u64* rbase = slotp(slot) + ((size_t)blk * BROWS) * ROWQ;
            if (trow == 0) {
                #pragma unroll
                for (int f = 0; f < 6; ++f) pub4(rbase + (3 + f) * ROWQ + 2 * c4, pc[3 + f]);
                #pragma unroll
                for (int f = 0; f < 3; ++f) pub4(rbase + (9 + f) * ROWQ + 2 * c4, pc[f]);
            } else if (trow == 7) {
                #pragma unroll
                for (int f = 0; f < 3; ++f) pub4(rbase + f * ROWQ + 2 * c4, pc[3 + f]);
            }
        }
    };

    // ================= INIT (iteration 0): concrete x_0=y, v_1 = nabla(y) =================
    {
        yv = ld4(y, j4);
        yv2 = have2 ? ld4(y, j4 + 64) : mk4(0, 0, 0, 0);
        xcur = yv; x2 = yv2;
        v0c = have2 ? f4sub(yv2, yv) : mk4(0, 0, 0, 0);
        v1c = gradw(yv, c4);
        float4 y3 = dn2 ? ld4(y, j4 + 128) : mk4(0, 0, 0, 0);
        v0c2 = dn2 ? f4sub(y3, yv2) : mk4(0, 0, 0, 0);
        v1c2 = gradw(yv2, c4);
        vm = (gh > 0) ? f4sub(yv, ld4(y, j4 - 64)) : mk4(0, 0, 0, 0);
        normpub(1);                           // ||v_1||^2 per-wave partials
        chi = 1.f / sqrtf(1.f + tau);         // chi_0
        sigs = sig / chi;                     // sigma_1
        expandF(0, true);                     // pieces of x_1, v_2 -> LDS + slot 0
        tau *= chi; sig = sigs;
        if (trow == 3) {
            float g0, g1; pollparts(1, g0, g1);
            if (c4 == 0) { sG[0] = g0; sG[1] = g1; }
        }
    }

    // ================= MAIN LOOP (s = 1..48) =================
    for (int s = 1; s < KSTEPS - 1; ++s) {
        barld();                              // B_a: prev LDS writes (+sG) -> this iter reads
        float al, be;
        { float g0 = sG[0], g1 = sG[1];
          al = lamb / fmaxf(sqrtf(g0), lamb);
          be = lamb / fmaxf(sqrtf(g1), lamb); }
        chi = 1.f / sqrtf(1.f + tau);
        sigs = sig / chi;
        const int ps = (s - 1) % 3;

        // halo polls (raw, then collapse with al/be)
        if (trow == 0) {
            if (tile > 0) {
                const u64* ra = slotp(ps) + ((size_t)(blk - 1) * BROWS) * ROWQ + 2 * c4;
                u64 a0, a1, a2, a3, a4, a5;
                for (;;) {
                    a0 = ldq(ra);            a1 = ldq(ra + 1);
                    a2 = ldq(ra + ROWQ);     a3 = ldq(ra + ROWQ + 1);
                    a4 = ldq(ra + 2 * ROWQ); a5 = ldq(ra + 2 * ROWQ + 1);
                    if (__all((a0 != SENT) && (a1 != SENT) && (a2 != SENT) &&
                              (a3 != SENT) && (a4 != SENT) && (a5 != SENT))) break;
                    __builtin_amdgcn_s_sleep(1);
                }
                vm = col3(unp(a0, a1), unp(a2, a3), unp(a4, a5), al, be);
            } else vm = mk4(0, 0, 0, 0);
        }
        if (trow == 7 && tile < 31) {
            const u64* rb = slotp(ps) + ((size_t)(blk + 1) * BROWS) * ROWQ + 2 * c4;
            u64 t[18];
            for (;;) {
                #pragma unroll
                for (int i = 0; i < 9; ++i) { t[2 * i] = ldq(rb + (3 + i) * ROWQ); t[2 * i + 1] = ldq(rb + (3 + i) * ROWQ + 1); }
                bool ok = true;
                #pragma unroll
                for (int i = 0; i < 18; ++i) ok = ok && (t[i] != SENT);
                if (__all(ok)) break;
                __builtin_amdgcn_s_sleep(1);
            }
            v0c2 = col3(unp(t[0], t[1]),   unp(t[2], t[3]),   unp(t[4], t[5]),   al, be);
            v1c2 = col3(unp(t[6], t[7]),   unp(t[8], t[9]),   unp(t[10], t[11]), al, be);
            x2   = col3(unp(t[12], t[13]), unp(t[14], t[15]), unp(t[16], t[17]), al, be);
        }
        asm volatile("" ::: "memory");

        // resets: slot (s+1)%3 holds step-(s-2) pieces; dead (gated by parts[s] via sG)
        if (s <= 47) {
            u64* rb2 = slotp((s + 1) % 3) + ((size_t)blk * BROWS) * ROWQ;
            if (trow == 0) {
                #pragma unroll
                for (int r = 3; r < 12; ++r) { stq(rb2 + r * ROWQ + 2 * c4, SENT); stq(rb2 + r * ROWQ + 2 * c4 + 1, SENT); }
            } else if (trow == 7) {
                #pragma unroll
                for (int r = 0; r < 3; ++r) { stq(rb2 + r * ROWQ + 2 * c4, SENT); stq(rb2 + r * ROWQ + 2 * c4 + 1, SENT); }
            }
        }

        // collapse: own row from registers, neighbors from LDS
        if (trow > 0) vm = col3(ldsF(trow - 1, 3), ldsF(trow - 1, 4), ldsF(trow - 1, 5), al, be);
        xcur = col3(pc[0], pc[1], pc[2], al, be);
        v0c  = col3(pc[3], pc[4], pc[5], al, be);
        v1c  = col3(pc[6], pc[7], pc[8], al, be);
        if (trow < 7) {
            x2   = col3(ldsF(trow + 1, 0), ldsF(trow + 1, 1), ldsF(trow + 1, 2), al, be);
            v0c2 = col3(ldsF(trow + 1, 3), ldsF(trow + 1, 4), ldsF(trow + 1, 5), al, be);
            v1c2 = col3(ldsF(trow + 1, 6), ldsF(trow + 1, 7), ldsF(trow + 1, 8), al, be);
        }
        normpub(s + 1);                       // ||v_{s+1}||^2 per-wave (max slack)
        barld();                              // B_b: LDS reads done before expand overwrites
        expandF(s % 3, true);
        tau *= chi; sig = sigs;
        if (trow == 3) {                      // wave 3: poll next step's norms into LDS
            float g0, g1; pollparts(s + 1, g0, g1);
            if (c4 == 0) { sG[0] = g0; sG[1] = g1; }
        }
    }

    // ================= ITERATION 49 (x-pieces only) + FINAL =================
    {
        barld();
        float al, be;
        { float g0 = sG[0], g1 = sG[1];
          al = lamb / fmaxf(sqrtf(g0), lamb);
          be = lamb / fmaxf(sqrtf(g1), lamb); }
        chi = 1.f / sqrtf(1.f + tau);         // chi_49
        const int ps = (KSTEPS - 2) % 3;      // 48%3 = 0
        if (trow == 0) {
            if (tile > 0) {
                const u64* ra = slotp(ps) + ((size_t)(blk - 1) * BROWS) * ROWQ + 2 * c4;
                u64 a0, a1, a2, a3, a4, a5;
                for (;;) {
                    a0 = ldq(ra);            a1 = ldq(ra + 1);
                    a2 = ldq(ra + ROWQ);     a3 = ldq(ra + ROWQ + 1);
                    a4 = ldq(ra + 2 * ROWQ); a5 = ldq(ra + 2 * ROWQ + 1);
                    if (__all((a0 != SENT) && (a1 != SENT) && (a2 != SENT) &&
                              (a3 != SENT) && (a4 != SENT) && (a5 != SENT))) break;
                    __builtin_amdgcn_s_sleep(1);
                }
                vm = col3(unp(a0, a1), unp(a2, a3), unp(a4, a5), al, be);
            } else vm = mk4(0, 0, 0, 0);
        }
        asm volatile("" ::: "memory");
        if (trow > 0) vm = col3(ldsF(trow - 1, 3), ldsF(trow - 1, 4), ldsF(trow - 1, 5), al, be);
        xcur = col3(pc[0], pc[1], pc[2], al, be);   // x_49
        v0c  = col3(pc[3], pc[4], pc[5], al, be);   // v_50
        v1c  = col3(pc[6], pc[7], pc[8], al, be);
        normpub(KSTEPS);                            // ||v_50||^2

        const float inv = 1.f / (1.f + tau), tin = tau * inv;
        float4 NT0 = nth(vm, gh > 0, v0c, have2);
        float4 NT1 = ntw(v1c, c4);
        float4 BASE = f4s(f4fma(tau, yv, xcur), inv);
        float4 xA = f4s(NT0, -tin), xB = f4s(NT1, -tin);

        float g0, g1;
        pollparts(KSTEPS, g0, g1);                  // gate: all blocks past piece reads
        const float a50 = lamb / fmaxf(sqrtf(g0), lamb);
        const float b50 = lamb / fmaxf(sqrtf(g1), lamb);
        float4 x50 = col3(BASE, xA, xB, a50, b50);
        float4 xt50 = f4fma(-chi, xcur, f4s(x50, 1.f + chi));
        const int iv4 = bc * 32768 + gh * 64 + c4;
        st4(xout, j4, x50);
        st4(xtout, j4, xt50);
        st4(uout, iv4, f4s(v0c, a50));
        st4(uout, iv4 + 16384, f4s(v1c, b50));
    }
}

extern "C" void kernel_launch(void* const* d_in, const int* in_sizes, int n_in,
                              void* d_out, int out_size, void* d_ws, size_t ws_size,
                              hipStream_t stream) {
    (void)in_sizes; (void)n_in; (void)out_size; (void)ws_size;
    const float* y     = (const float*)d_in[0];
    const float* lambd = (const float*)d_in[1];
    float* xout  = (float*)d_out;       // [0, NX)
    float* xtout = xout + NX;           // [NX, 2NX)
    float* uout  = xout + 2 * NX;       // [2NX, 2NX+NU)

    // slots 0,1 in d_out (4.72 MB <= 6.29 MB; all piece reads complete before final
    // output writes, gated by the parts[50] poll). slot 2 + parts in d_ws (~3.0 MB).
    u64* h0 = (u64*)d_out;
    u64* h1 = h0 + SLOTQ;
    u64* h2 = (u64*)d_ws;
    u64* parts = h2 + SLOTQ;            // [(KSTEPS+1)][NBLK*8] u64

    init_ws<<<SLOTQ / 256, 256, 0, stream>>>(h0, h1, h2, parts);
    cp_persist<<<NBLK, 512, 0, stream>>>(y, lambd, xout, xtout, uout, h0, h1, h2, parts);
}